// Round 13
// baseline (273.997 us; speedup 1.0000x reference)
//
#include <hip/hip_runtime.h>

#define NCLUSTER 512
#define NC 3
#define HW 65536
#define BLOCK 512                // 8 waves
#define NW 8                     // waves per block = cluster subsets
#define KSUB (NCLUSTER / NW)     // 64 clusters per wave
#define PPT 4                    // pixels per thread
#define PXB 256                  // pixels per block
#define EPS 1e-4f

// ---------------- real kernel: EXACTLY R12 (32.4 us, absmax 0) ----------------
__global__ __launch_bounds__(BLOCK, 8) void kmeans_assign(
    const float* __restrict__ x,
    const float* __restrict__ C,
    int* __restrict__ out)
{
    __shared__ float4 lc[NCLUSTER];
    __shared__ float  rb1[NW][PXB];
    __shared__ float  rb2[NW][PXB];
    __shared__ int    ridx[NW][PXB];
    __shared__ int    qpx[PXB];
    __shared__ int    qcnt;

    const int w = threadIdx.x >> 6;
    const int l = threadIdx.x & 63;
    const int B0 = blockIdx.x * PXB;
    const int pB = B0 & (HW - 1);
    const float* xb = x + (size_t)(B0 >> 16) * NC * HW;

    float x0[PPT], x1[PPT], x2[PPT];
#pragma unroll
    for (int i = 0; i < PPT; ++i) {
        int p = pB + l + i * 64;
        x0[i] = xb[p];
        x1[i] = xb[p + HW];
        x2[i] = xb[p + 2 * HW];
    }

    if (threadIdx.x == 0) qcnt = 0;
    {
        int k = threadIdx.x;
        double c0 = C[k * NC + 0];
        double c1 = C[k * NC + 1];
        double c2 = C[k * NC + 2];
        lc[k] = make_float4((float)c0, (float)c1, (float)c2,
                            (float)(0.5 * (c0 * c0 + c1 * c1 + c2 * c2)));
    }
    __syncthreads();

    float b1[PPT], b2[PPT];
    int id[PPT];
#pragma unroll
    for (int i = 0; i < PPT; ++i) { b1[i] = 1e30f; b2[i] = 1e30f; id[i] = 0; }

    const int k0 = w * KSUB;
#pragma unroll 4
    for (int k = 0; k < KSUB; ++k) {
        float4 c = lc[k0 + k];
#pragma unroll
        for (int i = 0; i < PPT; ++i) {
            float t = __builtin_fmaf(-x0[i], c.x, c.w);
            t = __builtin_fmaf(-x1[i], c.y, t);
            t = __builtin_fmaf(-x2[i], c.z, t);
            bool lt = t < b1[i];
            b2[i] = __builtin_amdgcn_fmed3f(t, b1[i], b2[i]);
            id[i] = lt ? (k0 + k) : id[i];
            b1[i] = fminf(t, b1[i]);
        }
    }

#pragma unroll
    for (int i = 0; i < PPT; ++i) {
        rb1[w][l + i * 64] = b1[i];
        rb2[w][l + i * 64] = b2[i];
        ridx[w][l + i * 64] = id[i];
    }
    __syncthreads();

    if (threadIdx.x < PXB) {
        const int t = threadIdx.x;
        float g1m = rb1[0][t];
        float g2m = rb2[0][t];
        int gi = ridx[0][t];
#pragma unroll
        for (int ww = 1; ww < NW; ++ww) {
            float a1 = rb1[ww][t];
            float a2 = rb2[ww][t];
            int ai = ridx[ww][t];
            bool lt = a1 < g1m;
            g2m = lt ? fminf(g1m, a2) : fminf(g2m, a1);
            gi = lt ? ai : gi;
            g1m = fminf(g1m, a1);
        }
        if (g2m - g1m < EPS) {
            qpx[atomicAdd(&qcnt, 1)] = t;
        } else {
            out[B0 + t] = gi;
        }
    }
    __syncthreads();

    const int n = qcnt;
    for (int e = w; e < n; e += NW) {
        const int t = qpx[e];
        const int p = pB + t;
        double X0 = (double)xb[p];
        double X1 = (double)xb[p + HW];
        double X2 = (double)xb[p + 2 * HW];
        double bd = 1e300;
        int bi = 0;
#pragma unroll
        for (int j = 0; j < NCLUSTER / 64; ++j) {
            int k = j * 64 + l;
            float4 c = lc[k];
            double d0 = X0 - (double)c.x;
            double d1 = X1 - (double)c.y;
            double d2 = X2 - (double)c.z;
            double d = d0 * d0 + d1 * d1 + d2 * d2;
            if (d < bd) { bd = d; bi = k; }
        }
#pragma unroll
        for (int m = 1; m < 64; m <<= 1) {
            double od = __shfl_xor(bd, m, 64);
            int oi = __shfl_xor(bi, m, 64);
            bool take = (od < bd) || (od == bd && oi < bi);
            bd = take ? od : bd;
            bi = take ? oi : bi;
        }
        if (l == 0) out[B0 + t] = bi;
    }
}

// ---------------- ablation kernels (write NOTHING; 4x internal reps) ----------
// MODE 0: full inner loop (LDS + 28 VALU)     -> isolates main-loop total
// MODE 1: 28 VALU only, c asm-blinded, no LDS -> isolates VALU pipe
// MODE 2: ds_read_b128 only, values asm-sunk  -> isolates LDS broadcast pipe
// MODE 3: LDS + 12 fma only, t asm-sunk       -> isolates fma vs bookkeeping
template<int MODE>
__device__ __forceinline__ void abl_body(const float* __restrict__ C) {
    __shared__ float4 lc[NCLUSTER];
    {
        int k = threadIdx.x;
        double c0 = C[k * NC + 0];
        double c1 = C[k * NC + 1];
        double c2 = C[k * NC + 2];
        lc[k] = make_float4((float)c0, (float)c1, (float)c2,
                            (float)(0.5 * (c0 * c0 + c1 * c1 + c2 * c2)));
    }
    __syncthreads();
    const int w = threadIdx.x >> 6;
    const int l = threadIdx.x & 63;
    float x0[4], x1[4], x2[4], b1[4], b2[4];
    int id[4];
#pragma unroll
    for (int i = 0; i < 4; ++i) {
        x0[i] = (float)(l + i * 64) + 0.001f * (float)blockIdx.x;
        x1[i] = x0[i] * 1.1f + 0.3f;
        x2[i] = x0[i] * 0.9f - 0.2f;
        b1[i] = 1e30f; b2[i] = 1e30f; id[i] = 0;
    }
    const int k0 = w * KSUB;
    float4 cr = lc[k0];
    float crx = cr.x, cry = cr.y, crz = cr.z, crw = cr.w;
    for (int r = 0; r < 4; ++r) {          // 4 reps of the real main loop
#pragma unroll 4
        for (int k = 0; k < KSUB; ++k) {
            float cx, cy, cz, cw;
            if (MODE == 1) {
                cx = crx; cy = cry; cz = crz; cw = crw;
                asm volatile("" : "+v"(cx), "+v"(cy), "+v"(cz), "+v"(cw));
            } else {
                float4 c = lc[k0 + k];
                cx = c.x; cy = c.y; cz = c.z; cw = c.w;
            }
            if (MODE == 2) {
                asm volatile("" :: "v"(cx), "v"(cy), "v"(cz), "v"(cw));
            } else {
#pragma unroll
                for (int i = 0; i < 4; ++i) {
                    float t = __builtin_fmaf(-x0[i], cx, cw);
                    t = __builtin_fmaf(-x1[i], cy, t);
                    t = __builtin_fmaf(-x2[i], cz, t);
                    if (MODE == 3) {
                        asm volatile("" :: "v"(t));
                    } else {
                        bool lt = t < b1[i];
                        b2[i] = __builtin_amdgcn_fmed3f(t, b1[i], b2[i]);
                        id[i] = lt ? (k0 + k) : id[i];
                        b1[i] = fminf(t, b1[i]);
                    }
                }
            }
        }
    }
    float acc = 0.f;
#pragma unroll
    for (int i = 0; i < 4; ++i) acc += b1[i] + b2[i] + (float)id[i];
    asm volatile("" :: "v"(acc));
}
__global__ __launch_bounds__(BLOCK, 8) void abl0_full(const float* __restrict__ C) { abl_body<0>(C); }
__global__ __launch_bounds__(BLOCK, 8) void abl1_valu(const float* __restrict__ C) { abl_body<1>(C); }
__global__ __launch_bounds__(BLOCK, 8) void abl2_lds (const float* __restrict__ C) { abl_body<2>(C); }
__global__ __launch_bounds__(BLOCK, 8) void abl3_fma (const float* __restrict__ C) { abl_body<3>(C); }

extern "C" void kernel_launch(void* const* d_in, const int* in_sizes, int n_in,
                              void* d_out, int out_size, void* d_ws, size_t ws_size,
                              hipStream_t stream) {
    const float* x = (const float*)d_in[0];
    const float* C = (const float*)d_in[1];
    int* out = (int*)d_out;

    int total = out_size;              // 262144
    int grid = total / PXB;            // 1024 blocks
    kmeans_assign<<<grid, BLOCK, 0, stream>>>(x, C, out);

    // Instrumentation dispatches (same geometry, no output writes).
    abl0_full<<<grid, BLOCK, 0, stream>>>(C);
    abl1_valu<<<grid, BLOCK, 0, stream>>>(C);
    abl2_lds <<<grid, BLOCK, 0, stream>>>(C);
    abl3_fma <<<grid, BLOCK, 0, stream>>>(C);
}

// Round 14
// 34.355 us; speedup vs baseline: 7.9754x; 7.9754x over previous
//
#include <hip/hip_runtime.h>

#define NCLUSTER 512
#define NC 3
#define HW 65536
#define BLOCK 512                // 8 waves
#define NW 8                     // waves per block = cluster subsets
#define NPW (NCLUSTER / NW / 2)  // 32 cluster PAIRS per wave
#define PPT 4                    // pixels per thread
#define PXB 256                  // pixels per block
#define EPS 1e-4f

typedef float f32x2 __attribute__((ext_vector_type(2)));

// Certified-exact fp32 path (absmax 0, R8-R12): argmin_k d_k == argmin_k t_k,
// t_k = 0.5*||C_k||^2 - x.C_k; exact global top-2 certifies when gap >= EPS;
// near-ties queue-compacted + resolved in exact fp64.
// R13 ablation: kernel is VALU-ISSUE-bound (pure-VALU ablation = 27us @ 90%
// VALUBusy; LDS ablations all faster). R14: process cluster PAIRS with
// v_pk_fma_f32 (plain packed form, exactness = IEEE fp32 fma per half):
// 3 pk_fma + 8 bookkeeping per 2 clusters = 5.5 ops/cluster-px vs 7.
__global__ __launch_bounds__(BLOCK, 4) void kmeans_assign(
    const float* __restrict__ x,   // [4,3,256,256]
    const float* __restrict__ C,   // [512,3]
    int* __restrict__ out)         // [4,65536]
{
    __shared__ float4 lcP0[NCLUSTER / 2];  // {cx_a, cx_b, cy_a, cy_b}  4 KB
    __shared__ float4 lcP1[NCLUSTER / 2];  // {cz_a, cz_b, cw_a, cw_b}  4 KB
    __shared__ float  rb1[NW][PXB];        //                           8 KB
    __shared__ float  rb2[NW][PXB];        //                           8 KB
    __shared__ int    ridx[NW][PXB];       //                           8 KB
    __shared__ int    qpx[PXB];            //                           1 KB
    __shared__ int    qcnt;

    const int w = threadIdx.x >> 6;
    const int l = threadIdx.x & 63;
    const int B0 = blockIdx.x * PXB;
    const int pB = B0 & (HW - 1);
    const float* xb = x + (size_t)(B0 >> 16) * NC * HW;

    // Issue x loads first; global latency overlaps the staging below.
    float x0[PPT], x1[PPT], x2[PPT];
#pragma unroll
    for (int i = 0; i < PPT; ++i) {
        int p = pB + l + i * 64;
        x0[i] = xb[p];
        x1[i] = xb[p + HW];
        x2[i] = xb[p + 2 * HW];
    }

    if (threadIdx.x == 0) qcnt = 0;
    if (threadIdx.x < NCLUSTER / 2) {      // stage cluster pair j
        int j = threadIdx.x;
        const float* ca = C + (2 * j) * NC;
        double a0 = ca[0], a1 = ca[1], a2 = ca[2];
        double e0 = ca[3], e1 = ca[4], e2 = ca[5];
        lcP0[j] = make_float4((float)a0, (float)e0, (float)a1, (float)e1);
        lcP1[j] = make_float4((float)a2, (float)e2,
                              (float)(0.5 * (a0 * a0 + a1 * a1 + a2 * a2)),
                              (float)(0.5 * (e0 * e0 + e1 * e1 + e2 * e2)));
    }
    __syncthreads();

    // Pair-broadcast copies of -x (pk operands are 64-bit reg pairs).
    f32x2 NX0[PPT], NX1[PPT], NX2[PPT];
#pragma unroll
    for (int i = 0; i < PPT; ++i) {
        NX0[i] = (f32x2){-x0[i], -x0[i]};
        NX1[i] = (f32x2){-x1[i], -x1[i]};
        NX2[i] = (f32x2){-x2[i], -x2[i]};
    }

    float b1[PPT], b2[PPT];
    int id[PPT];
#pragma unroll
    for (int i = 0; i < PPT; ++i) { b1[i] = 1e30f; b2[i] = 1e30f; id[i] = 0; }

    const int j0 = w * NPW;
#pragma unroll 4
    for (int j = 0; j < NPW; ++j) {
        float4 Pa = lcP0[j0 + j];           // uniform ds_read_b128
        float4 Pb = lcP1[j0 + j];           // uniform ds_read_b128
        f32x2 cx2 = (f32x2){Pa.x, Pa.y};
        f32x2 cy2 = (f32x2){Pa.z, Pa.w};
        f32x2 cz2 = (f32x2){Pb.x, Pb.y};
        f32x2 cw2 = (f32x2){Pb.z, Pb.w};
        const int ka = (j0 + j) * 2;
#pragma unroll
        for (int i = 0; i < PPT; ++i) {
            f32x2 T;
            asm("v_pk_fma_f32 %0, %1, %2, %3"
                : "=v"(T) : "v"(NX0[i]), "v"(cx2), "v"(cw2));
            asm("v_pk_fma_f32 %0, %1, %2, %0"
                : "+v"(T) : "v"(NX1[i]), "v"(cy2));
            asm("v_pk_fma_f32 %0, %1, %2, %0"
                : "+v"(T) : "v"(NX2[i]), "v"(cz2));
            float ta = T.x, tb = T.y;
            float tmn = fminf(ta, tb);
            int pidx = ka + (tb < ta);                 // tie -> ka (lower k)
            // exact 2nd-best of {b1,b2,ta,tb}: med3 covers all 3 cases
            b2[i] = fminf(b2[i], __builtin_amdgcn_fmed3f(ta, tb, b1[i]));
            bool lt = tmn < b1[i];                     // strict: first k wins
            id[i] = lt ? pidx : id[i];
            b1[i] = fminf(tmn, b1[i]);
        }
    }

#pragma unroll
    for (int i = 0; i < PPT; ++i) {
        rb1[w][l + i * 64] = b1[i];
        rb2[w][l + i * 64] = b2[i];
        ridx[w][l + i * 64] = id[i];
    }
    __syncthreads();

    // Merge subsets (w ascending -> lowest cluster index wins ties).
    if (threadIdx.x < PXB) {
        const int t = threadIdx.x;
        float g1m = rb1[0][t];
        float g2m = rb2[0][t];
        int gi = ridx[0][t];
#pragma unroll
        for (int ww = 1; ww < NW; ++ww) {
            float a1 = rb1[ww][t];
            float a2 = rb2[ww][t];
            int ai = ridx[ww][t];
            bool lt = a1 < g1m;
            g2m = lt ? fminf(g1m, a2) : fminf(g2m, a1);
            gi = lt ? ai : gi;
            g1m = fminf(g1m, a1);
        }
        if (g2m - g1m < EPS) {
            qpx[atomicAdd(&qcnt, 1)] = t;
        } else {
            out[B0 + t] = gi;
        }
    }
    __syncthreads();

    // Wave-cooperative exact fp64 resolve (validated absmax 0), smallest-k ties.
    const int n = qcnt;
    for (int e = w; e < n; e += NW) {
        const int t = qpx[e];
        const int p = pB + t;
        double X0 = (double)xb[p];
        double X1 = (double)xb[p + HW];
        double X2 = (double)xb[p + 2 * HW];
        double bd = 1e300;
        int bi = 0;
#pragma unroll
        for (int jj = 0; jj < NCLUSTER / 64; ++jj) {
            int k = jj * 64 + l;            // ascending per lane
            float4 Pa = lcP0[k >> 1];
            float4 Pb = lcP1[k >> 1];
            bool h = (k & 1) != 0;
            float cx = h ? Pa.y : Pa.x;
            float cy = h ? Pa.w : Pa.z;
            float cz = h ? Pb.y : Pb.x;
            double d0 = X0 - (double)cx;
            double d1 = X1 - (double)cy;
            double d2 = X2 - (double)cz;
            double d = d0 * d0 + d1 * d1 + d2 * d2;
            if (d < bd) { bd = d; bi = k; }
        }
#pragma unroll
        for (int m = 1; m < 64; m <<= 1) {
            double od = __shfl_xor(bd, m, 64);
            int oi = __shfl_xor(bi, m, 64);
            bool take = (od < bd) || (od == bd && oi < bi);
            bd = take ? od : bd;
            bi = take ? oi : bi;
        }
        if (l == 0) out[B0 + t] = bi;
    }
}

extern "C" void kernel_launch(void* const* d_in, const int* in_sizes, int n_in,
                              void* d_out, int out_size, void* d_ws, size_t ws_size,
                              hipStream_t stream) {
    const float* x = (const float*)d_in[0];
    const float* C = (const float*)d_in[1];
    int* out = (int*)d_out;

    int total = out_size;              // 262144
    int grid = total / PXB;            // 1024 blocks
    kmeans_assign<<<grid, BLOCK, 0, stream>>>(x, C, out);
}